// Round 1
// baseline (943.376 us; speedup 1.0000x reference)
//
#include <hip/hip_runtime.h>
#include <stdint.h>

// BinaryDense: out[N,128] = inputs[N,128] @ w_bin[128,128], w_bin = ±1 from
// JAX threefry-partitionable bernoulli(hard_sigmoid(weight)).
//
// PRNG hypothesis H1 (this round): partitionable threefry —
//   bits[i] = o0 ^ o1 where (o0,o1) = threefry2x32(key=(0,seed), x0=0, x1=i)
// Fallbacks if absmax is large: H2 legacy split-iota (bits[j]=o0 of pair
// (j, j+8192)); H3 swapped counter order; H4 o0-only.

typedef _Float16 half8 __attribute__((ext_vector_type(8)));
typedef float f32x4 __attribute__((ext_vector_type(4)));

__device__ __forceinline__ uint32_t rotl32(uint32_t x, int n) {
    return (x << n) | (x >> (32 - n));
}

__device__ __forceinline__ void threefry2x32(uint32_t k0, uint32_t k1,
                                             uint32_t x0, uint32_t x1,
                                             uint32_t& o0, uint32_t& o1) {
    const uint32_t ks0 = k0, ks1 = k1, ks2 = 0x1BD11BDAu ^ k0 ^ k1;
    x0 += ks0; x1 += ks1;
#define TF_ROUND(r) { x0 += x1; x1 = rotl32(x1, (r)); x1 ^= x0; }
    TF_ROUND(13) TF_ROUND(15) TF_ROUND(26) TF_ROUND(6)
    x0 += ks1; x1 += ks2 + 1u;
    TF_ROUND(17) TF_ROUND(29) TF_ROUND(16) TF_ROUND(24)
    x0 += ks2; x1 += ks0 + 2u;
    TF_ROUND(13) TF_ROUND(15) TF_ROUND(26) TF_ROUND(6)
    x0 += ks0; x1 += ks1 + 3u;
    TF_ROUND(17) TF_ROUND(29) TF_ROUND(16) TF_ROUND(24)
    x0 += ks1; x1 += ks2 + 4u;
    TF_ROUND(13) TF_ROUND(15) TF_ROUND(26) TF_ROUND(6)
    x0 += ks2; x1 += ks0 + 5u;
#undef TF_ROUND
    o0 = x0; o1 = x1;
}

// Kernel 1: binarize weight -> f16 (+1/-1) stored in MFMA B-fragment order.
// Weight flat index i = k*128 + n  (k in D, n in F).
// B-frag addr for 16x16x32: tile=n>>4, kstep=k>>5, q=(k>>3)&3, j=k&7,
// lane=q*16+(n&15) -> frag[((tile*4+kstep)*64+lane)*8 + j]
__global__ void binarize_kernel(const float* __restrict__ weight,
                                const int* __restrict__ seed_p,
                                const int* __restrict__ train_p,
                                unsigned short* __restrict__ bfrag) {
    const int i = blockIdx.x * 256 + threadIdx.x;  // 0..16383
    const uint32_t seed_lo = (uint32_t)(*seed_p);  // jax key = (hi=0, lo=seed)
    const int training = *train_p;
    const float w = weight[i];

    unsigned short sign_bits;
    if (training) {
        uint32_t o0, o1;
        threefry2x32(0u, seed_lo, 0u, (uint32_t)i, o0, o1);
        const uint32_t bits = o0 ^ o1;  // partitionable 32-bit fold
        const float u = __uint_as_float((bits >> 9) | 0x3F800000u) - 1.0f;
        float p = (w + 1.0f) * 0.5f;
        p = fminf(fmaxf(p, 0.0f), 1.0f);
        sign_bits = (u < p) ? 0x3C00u : 0xBC00u;  // f16 +1 : -1
    } else {
        sign_bits = (w > 0.0f) ? 0x3C00u : 0xBC00u;
    }

    const int k = i >> 7, n = i & 127;
    const int tile = n >> 4, kstep = k >> 5, q = (k >> 3) & 3, j = k & 7;
    const int lane = q * 16 + (n & 15);
    bfrag[((tile * 4 + kstep) * 64 + lane) * 8 + j] = sign_bits;
}

// Kernel 2: tall-skinny GEMM. Block = 256 thr (4 waves); B (32 KB f16 frags)
// in LDS; grid-stride over 64-row strips, wave computes 16 rows x 128 cols
// with 8 col-tiles x 4 k-steps of mfma_f32_16x16x32_f16.
__global__ __launch_bounds__(256, 4)
void gemm_bin_kernel(const float* __restrict__ A,
                     const unsigned short* __restrict__ bfrag,
                     float* __restrict__ out,
                     int nstrips) {
    __shared__ unsigned short ldsB[16384];  // 32 KB
    {
        const uint4* src = (const uint4*)bfrag;
        uint4* dst = (uint4*)ldsB;
        const int t = threadIdx.x;
#pragma unroll
        for (int i = 0; i < 8; ++i) dst[t + i * 256] = src[t + i * 256];
    }
    __syncthreads();

    const int lane = threadIdx.x & 63;
    const int wv = threadIdx.x >> 6;
    const int m = lane & 15;   // A row within wave tile / output col within tile
    const int q = lane >> 4;   // quad

    for (int s = blockIdx.x; s < nstrips; s += gridDim.x) {
        const int64_t base_row = (int64_t)s * 64 + wv * 16;
        const float* arow = A + (base_row + m) * 128 + q * 8;

        // Issue all 8 global loads first (MLP), then convert.
        float4 fbuf[8];
#pragma unroll
        for (int kk = 0; kk < 4; ++kk) {
            fbuf[2 * kk]     = *(const float4*)(arow + kk * 32);
            fbuf[2 * kk + 1] = *(const float4*)(arow + kk * 32 + 4);
        }
        half8 afr[4];
#pragma unroll
        for (int kk = 0; kk < 4; ++kk) {
            afr[kk][0] = (_Float16)fbuf[2 * kk].x;
            afr[kk][1] = (_Float16)fbuf[2 * kk].y;
            afr[kk][2] = (_Float16)fbuf[2 * kk].z;
            afr[kk][3] = (_Float16)fbuf[2 * kk].w;
            afr[kk][4] = (_Float16)fbuf[2 * kk + 1].x;
            afr[kk][5] = (_Float16)fbuf[2 * kk + 1].y;
            afr[kk][6] = (_Float16)fbuf[2 * kk + 1].z;
            afr[kk][7] = (_Float16)fbuf[2 * kk + 1].w;
        }

        float* orow = out + (base_row + q * 4) * 128 + m;
#pragma unroll
        for (int t = 0; t < 8; ++t) {
            f32x4 acc = {0.f, 0.f, 0.f, 0.f};
#pragma unroll
            for (int kk = 0; kk < 4; ++kk) {
                const half8 bfr = *(const half8*)(&ldsB[((t * 4 + kk) * 64 + lane) * 8]);
                acc = __builtin_amdgcn_mfma_f32_16x16x32_f16(afr[kk], bfr, acc, 0, 0, 0);
            }
            // C/D layout: col = lane&15, row = (lane>>4)*4 + reg  [m89/m91]
#pragma unroll
            for (int r = 0; r < 4; ++r) orow[r * 128 + t * 16] = acc[r];
        }
    }
}

extern "C" void kernel_launch(void* const* d_in, const int* in_sizes, int n_in,
                              void* d_out, int out_size, void* d_ws, size_t ws_size,
                              hipStream_t stream) {
    const float* A = (const float*)d_in[0];       // [N,128] fp32
    const float* W = (const float*)d_in[1];       // [128,128] fp32
    const int* seed = (const int*)d_in[2];
    const int* train = (const int*)d_in[3];
    float* out = (float*)d_out;
    unsigned short* bfrag = (unsigned short*)d_ws;  // 16384 f16 = 32 KB

    const int N = in_sizes[0] / 128;
    const int nstrips = N / 64;

    binarize_kernel<<<64, 256, 0, stream>>>(W, seed, train, bfrag);

    int grid = 4096;
    if (grid > nstrips) grid = nstrips;
    gemm_bin_kernel<<<grid, 256, 0, stream>>>(A, bfrag, out, nstrips);
}